// Round 4
// baseline (1099.939 us; speedup 1.0000x reference)
//
#include <hip/hip_runtime.h>
#include <math.h>

#define B_ 2
#define V_ 8
#define C_ 64
#define HW_ 16384
#define A_ 256
#define P_ 65536
#define CO_ 192
#define ICP1 224
#define ICP2 192

// workspace layout (bytes)
#define OFF_ACC   0ull
#define SZ_ACC    (2ull*65536*192*4)          // reused: atlas acc -> h1raw -> h2
#define OFF_CNT   (OFF_ACC + SZ_ACC)
#define SZ_CNT    (2ull*3*65536*4)
#define OFF_CTXB  (OFF_CNT + SZ_CNT)          // ctx NHWC bf16, 224-ch padded
#define SZ_CTXB   (2ull*65536*224*2)
#define OFF_H1A   (OFF_CTXB + SZ_CTXB)        // h1 activated, NHWC bf16, 192 ch
#define SZ_H1A    (2ull*65536*192*2)
#define OFF_W1    (OFF_H1A + SZ_H1A)
#define SZ_W1     (9ull*192*224*2)
#define OFF_W2    (OFF_W1 + SZ_W1)
#define SZ_W2     (9ull*192*192*2)
#define OFF_SM    (OFF_W2 + SZ_W2 + 256)

#define SM_STATS1 0
#define SM_STATS2 256
#define SM_SCALE  512
#define SM_POOLED 1024
#define SM_GATE   2560
#define SM_RAWU   8192

// d_out offsets (floats)
#define OUT_B    8388608
#define OUT_COV  25165824
#define OUT_UNC  25296896
#define OUT_CONF 25427968

typedef __attribute__((ext_vector_type(4))) float f32x4;
typedef __attribute__((ext_vector_type(8))) short bf16x8;

__device__ __forceinline__ float sigmoidf_(float x){ return 1.f/(1.f+expf(-x)); }
__device__ __forceinline__ float bf2f(unsigned short h){ return __uint_as_float(((unsigned)h)<<16); }
__device__ __forceinline__ unsigned short f2bf(float f){
  unsigned u = __float_as_uint(f);
  return (unsigned short)((u + 0x7fffu + ((u>>16)&1u)) >> 16);
}

// ---------------- K0: weight prep (transpose+pad+bf16) ----------------
__global__ __launch_bounds__(256) void k_prep(const float* __restrict__ c1w,
    const float* __restrict__ c2w, unsigned short* __restrict__ w1p, unsigned short* __restrict__ w2p)
{
  int idx = blockIdx.x*256 + threadIdx.x;
  const int N1 = 9*192*224;
  if (idx < N1){
    int ic = idx % 224; int oc = (idx/224) % 192; int k = idx/(224*192);
    float v = (ic < 194) ? c1w[(size_t)(oc*194+ic)*9 + k] : 0.f;
    w1p[idx] = f2bf(v);
  } else {
    int i2 = idx - N1;
    if (i2 < 9*192*192){
      int ic = i2 % 192; int oc = (i2/192) % 192; int k = i2/(192*192);
      w2p[i2] = f2bf(c2w[(size_t)(oc*192+ic)*9 + k]);
    }
  }
}

// ---------------- K1: fused tri-branch scatter ----------------
__global__ __launch_bounds__(256) void k_fuse(const float* __restrict__ vf,
    const float* __restrict__ uvs, const float* __restrict__ masks,
    const float* __restrict__ wgp, const float* __restrict__ wbp, const float* __restrict__ whp,
    float* __restrict__ acc, float* __restrict__ cnt)
{
  __shared__ __align__(16) float sf[64*65];
  __shared__ int sidx[64];
  __shared__ int svalid[64];
  __shared__ float sw[3];
  int t = threadIdx.x;
  int pix0 = blockIdx.x*64;
  int b   = pix0 / (V_*HW_);
  int rem = pix0 % (V_*HW_);
  int v   = rem / HW_;
  int p2  = rem % HW_;
  size_t vbase = ((size_t)(b*V_+v))*C_*HW_;
  for (int i=0;i<16;i++){
    int f = t + i*256;
    int c = f>>6, px = f&63;
    sf[c*65+px] = vf[vbase + (size_t)c*HW_ + p2 + px];
  }
  if (t<64){
    const float* u2 = uvs + (((size_t)(b*V_+v))*HW_ + p2 + t)*2;
    float ux = u2[0], uy = u2[1];
    int fin = isfinite(ux) && isfinite(uy);
    float su = fin?ux:0.f, svv = fin?uy:0.f;
    float cu = fminf(fmaxf(su,0.f),1.f);
    float cv = fminf(fmaxf(svv,0.f),1.f);
    int xi = (int)rintf(cu*255.f);
    int yi = (int)rintf((1.f-cv)*255.f);
    sidx[t] = yi*256+xi;
    float m = masks[((size_t)(b*V_+v))*HW_ + p2 + t];
    svalid[t] = (m>0.5f) && fin;
  }
  if (t<3){
    const float* wp = (t==0)?wgp:((t==1)?wbp:whp);
    sw[t] = fmaxf(wp[b*V_+v], 0.f);
  }
  __syncthreads();
  int wave = t>>6, lane = t&63;
  float w0 = sw[0], w1 = sw[1], w2 = sw[2];
  for (int i=0;i<16;i++){
    int px = wave*16+i;
    if (!svalid[px]) continue;
    int bin = sidx[px];
    float val = sf[lane*65+px];
    size_t base = ((size_t)b*P_ + bin)*192;
    if (w0>0.f) atomicAdd(&acc[base + lane],        val*w0);
    if (w1>0.f) atomicAdd(&acc[base + 64 + lane],   val*w1);
    if (w2>0.f) atomicAdd(&acc[base + 128 + lane],  val*w2);
    if (lane<3){
      float wv = sw[lane];
      if (wv>0.f) atomicAdd(&cnt[((size_t)(b*3+lane))*P_ + bin], wv);
    }
  }
}

// ---------------- K2: finalize atlases -> ctx bf16 NHWC, coverage, raw unc ----------------
__global__ __launch_bounds__(256) void k_finalize(const float* __restrict__ acc,
      const float* __restrict__ cnt, unsigned short* __restrict__ ctxb,
      float* __restrict__ out_cov, float* __restrict__ raw_unc, int* __restrict__ scale)
{
  __shared__ __align__(16) float sv[64*193];
  __shared__ float sc[3][64];
  __shared__ float up[256];
  __shared__ float s_cov[64];
  __shared__ float s_unc[64];
  int t = threadIdx.x;
  int bin0 = blockIdx.x*64;
  int b = bin0 >> 16;
  int p0 = bin0 & 65535;
  size_t abase = ((size_t)b*P_ + p0)*192;
  for (int i=0;i<48;i++){
    int f = t + i*256;
    int bl = f/192, c = f - bl*192;
    sv[bl*193+c] = acc[abase + f];
  }
  if (t<192){
    int br = t>>6, bl = t&63;
    sc[br][bl] = cnt[((size_t)(b*3+br))*P_ + p0 + bl];
  }
  __syncthreads();
  {
    int bl = t>>2, q = t&3;
    float dg = 1.f/fmaxf(sc[0][bl],1.f);
    float db = 1.f/fmaxf(sc[1][bl],1.f);
    float dh = 1.f/fmaxf(sc[2][bl],1.f);
    float s = 0.f;
    for (int j=0;j<16;j++){
      int c = q*16+j;
      float fg = sv[bl*193+c]*dg;
      float fb = sv[bl*193+64+c]*db;
      float fh = sv[bl*193+128+c]*dh;
      sv[bl*193+c]=fg; sv[bl*193+64+c]=fb; sv[bl*193+128+c]=fh;
      float m = (fg+fb+fh)*(1.f/3.f);
      float d0=fg-m, d1=fb-m, d2=fh-m;
      s += d0*d0+d1*d1+d2*d2;
    }
    up[t] = s;
  }
  __syncthreads();
  if (t<64){
    float tot = up[t*4]+up[t*4+1]+up[t*4+2]+up[t*4+3];
    float u = sqrtf(tot*(1.f/192.f));
    float vg = sc[0][t]>0.f?1.f:0.f;
    float vb = sc[1][t]>0.f?1.f:0.f;
    float vh = sc[2][t]>0.f?1.f:0.f;
    float cov = fminf(fmaxf((vg+vb+vh)*(1.f/3.f),0.f),1.f);
    s_cov[t] = cov; s_unc[t] = u;
    out_cov[(size_t)b*P_ + p0 + t] = cov;
    raw_unc[(size_t)b*P_ + p0 + t] = u;
    atomicMax(&scale[b], __float_as_int(u));
  }
  __syncthreads();
  for (int f=t; f<1792; f+=256){
    int cg = f % 28, bl = f / 28;
    int c0 = cg*8;
    unsigned short h[8];
    #pragma unroll
    for (int j=0;j<8;j++){
      int c = c0+j;
      float vv;
      if (c < 192)      vv = sv[bl*193+c];
      else if (c==192)  vv = s_cov[bl];
      else if (c==193)  vv = s_unc[bl];
      else              vv = 0.f;
      h[j] = f2bf(vv);
    }
    *(uint4*)&ctxb[((size_t)b*P_ + p0 + bl)*ICP1 + c0] = *(uint4*)h;
  }
}

// ---------------- K3: normalize uncertainty ----------------
__global__ __launch_bounds__(256) void k_norm_unc(unsigned short* __restrict__ ctxb,
    const int* __restrict__ scale, const float* __restrict__ raw_unc,
    const float* __restrict__ out_cov, float* __restrict__ out_unc)
{
  int tid = blockIdx.x*256 + threadIdx.x;
  int b = tid >> 16;
  float s = fmaxf(__int_as_float(scale[b]), 1e-6f);
  float u = raw_unc[tid];
  float cov = out_cov[tid];
  float un = fminf(fmaxf(u/s,0.f),1.f)*cov;
  out_unc[tid] = un;
  ctxb[(size_t)tid*ICP1 + 193] = f2bf(un);
}

// ---------------- conv 3x3 via MFMA bf16 implicit GEMM, 2-row blocks ----------------
// tile: 64 oc x 256 px x 2 rows. Per chunk: stage 4 input rows ONCE (fat stage),
// then per-ky small weight stage + compute. GN group stats fused into epilogue.
template<int ICP, int CHUNKS>
__global__ __launch_bounds__(256,2) void k_conv3(const unsigned short* __restrict__ X,
    const unsigned short* __restrict__ Wp, const float* __restrict__ bias, float* __restrict__ Y,
    double* __restrict__ stats)
{
  __shared__ short s_in[4*258*32];   // 66,048 B
  __shared__ short s_w[192*32];      // 12,288 B
  __shared__ float sgn[16];
  int t = threadIdx.x;
  int y0 = blockIdx.x*2;
  int oc0 = blockIdx.y*64;
  int b = blockIdx.z;
  int wv = t>>6, lane = t&63, l15 = lane&15, quad = lane>>4;
  if (t<16) sgn[t]=0.f;
  f32x4 acc[2][4][4];
  #pragma unroll
  for (int mt=0;mt<4;mt++){
    float4 bv = *(const float4*)&bias[oc0 + mt*16 + quad*4];
    f32x4 iv; iv.x=bv.x; iv.y=bv.y; iv.z=bv.z; iv.w=bv.w;
    #pragma unroll
    for (int rr=0;rr<2;rr++)
      #pragma unroll
      for (int nt=0;nt<4;nt++) acc[rr][mt][nt]=iv;
  }
  const unsigned short* Xb = X + (size_t)b*P_*ICP;
  for (int ch=0; ch<CHUNKS; ++ch){
    int ic0 = ch*32;
    __syncthreads();
    // fat stage: 4 input rows x 258 px x 32 ic (4128 uint4)
    for (int f=t; f<4128; f+=256){
      int row = f/1032; int rem = f - row*1032;
      int xi = rem>>2, icq = rem&3;
      int gx = xi - 1, gy = y0 - 1 + row;
      uint4 vval = make_uint4(0,0,0,0);
      if ((unsigned)gx < 256u && (unsigned)gy < 256u)
        vval = *(const uint4*)&Xb[(size_t)(gy*256+gx)*ICP + ic0 + icq*8];
      *(uint4*)&s_in[row*8256 + xi*32 + ((icq ^ ((xi>>1)&3)))*8] = vval;
    }
    // stage weights ky=0
    for (int f=t; f<768; f+=256){
      int icq = f&3, oc = (f>>2)&63, kx = f>>8;
      uint4 vval = *(const uint4*)&Wp[(size_t)((0*3+kx)*192 + oc0 + oc)*ICP + ic0 + icq*8];
      int r = kx*64 + oc;
      *(uint4*)&s_w[r*32 + ((icq ^ ((r>>1)&3)))*8] = vval;
    }
    __syncthreads();
    for (int ky=0; ky<3; ky++){
      #pragma unroll
      for (int kx=0;kx<3;kx++){
        bf16x8 Af[4], Bf[2][4];
        #pragma unroll
        for (int mt=0;mt<4;mt++){
          int r = kx*64 + mt*16 + l15;
          Af[mt] = *(const bf16x8*)&s_w[r*32 + (((quad ^ ((r>>1)&3)))&3)*8];
        }
        #pragma unroll
        for (int rr=0;rr<2;rr++){
          int ri = rr + ky;
          #pragma unroll
          for (int nt=0;nt<4;nt++){
            int x = wv*64 + nt*16 + l15 + kx;
            Bf[rr][nt] = *(const bf16x8*)&s_in[ri*8256 + x*32 + (((quad ^ ((x>>1)&3)))&3)*8];
          }
        }
        #pragma unroll
        for (int mt=0;mt<4;mt++)
          #pragma unroll
          for (int rr=0;rr<2;rr++)
            #pragma unroll
            for (int nt=0;nt<4;nt++)
              acc[rr][mt][nt] = __builtin_amdgcn_mfma_f32_16x16x32_bf16(Af[mt], Bf[rr][nt], acc[rr][mt][nt], 0, 0, 0);
      }
      if (ky<2){
        __syncthreads();
        for (int f=t; f<768; f+=256){
          int icq = f&3, oc = (f>>2)&63, kx = f>>8;
          uint4 vval = *(const uint4*)&Wp[(size_t)(((ky+1)*3+kx)*192 + oc0 + oc)*ICP + ic0 + icq*8];
          int r = kx*64 + oc;
          *(uint4*)&s_w[r*32 + ((icq ^ ((r>>1)&3)))*8] = vval;
        }
        __syncthreads();
      }
    }
  }
  // store + fused GN stats
  float* Yb = Y + (size_t)b*P_*192;
  #pragma unroll
  for (int rr=0;rr<2;rr++){
    int y = y0 + rr;
    #pragma unroll
    for (int mt=0;mt<4;mt++){
      int oc = oc0 + mt*16 + quad*4;
      #pragma unroll
      for (int nt=0;nt<4;nt++){
        int px = wv*64 + nt*16 + l15;
        *(f32x4*)&Yb[(size_t)(y*256+px)*192 + oc] = acc[rr][mt][nt];
      }
    }
  }
  #pragma unroll
  for (int mt=0;mt<4;mt++){
    #pragma unroll
    for (int j=0;j<4;j++){
      float s=0.f, q=0.f;
      #pragma unroll
      for (int rr=0;rr<2;rr++)
        #pragma unroll
        for (int nt=0;nt<4;nt++){
          float vv = acc[rr][mt][nt][j];
          s += vv; q += vv*vv;
        }
      #pragma unroll
      for (int off=1; off<16; off<<=1){
        s += __shfl_xor(s, off);
        q += __shfl_xor(q, off);
      }
      if (l15==0){
        int g = (oc0 + mt*16 + quad*4 + j)/24;
        atomicAdd(&sgn[(g&7)*2],   s);
        atomicAdd(&sgn[(g&7)*2+1], q);
      }
    }
  }
  __syncthreads();
  if (t<16){
    int g = t>>1;
    atomicAdd(&stats[(size_t)(b*8+g)*2 + (t&1)], (double)sgn[t]);
  }
}

// ---------------- GN apply + SiLU -> bf16 NHWC (for conv2) ----------------
__global__ __launch_bounds__(256) void k_gn1_apply(const float* __restrict__ x, const double* __restrict__ stats,
    const float* __restrict__ gs, const float* __restrict__ gb, unsigned short* __restrict__ y)
{
  size_t i8 = ((size_t)blockIdx.x*256 + threadIdx.x)*8;
  int b = (int)(i8 / ((size_t)192*P_));
  int c = (int)(i8 % 192);
  int bg = b*8 + c/24;
  const double N = 24.0*65536.0;
  double mu = stats[bg*2]/N;
  double var = stats[bg*2+1]/N - mu*mu;
  float rstd = 1.0f/sqrtf((float)var + 1e-5f);
  float mean = (float)mu;
  float4 sA = *(const float4*)&gs[c];
  float4 sB = *(const float4*)&gs[c+4];
  float4 bA = *(const float4*)&gb[c];
  float4 bB = *(const float4*)&gb[c+4];
  float4 v0 = *(const float4*)&x[i8];
  float4 v1 = *(const float4*)&x[i8+4];
  float xin[8] = {v0.x,v0.y,v0.z,v0.w,v1.x,v1.y,v1.z,v1.w};
  float scl[8] = {sA.x,sA.y,sA.z,sA.w,sB.x,sB.y,sB.z,sB.w};
  float bia[8] = {bA.x,bA.y,bA.z,bA.w,bB.x,bB.y,bB.z,bB.w};
  unsigned short h[8];
  #pragma unroll
  for (int i=0;i<8;i++){
    float xn = (xin[i]-mean)*rstd*scl[i] + bia[i];
    h[i] = f2bf(xn*sigmoidf_(xn));
  }
  *(uint4*)&y[i8] = *(uint4*)h;
}

// ---------------- GN apply + SiLU in place fp32 (h2) + fused global pool ----------------
__global__ __launch_bounds__(256) void k_gn2_apply(float* __restrict__ x, const double* __restrict__ stats,
    const float* __restrict__ gs, const float* __restrict__ gb, float* __restrict__ pooled)
{
  __shared__ float pl[192];
  int t = threadIdx.x;
  if (t<192) pl[t]=0.f;
  __syncthreads();
  size_t i8 = ((size_t)blockIdx.x*256 + t)*8;
  int b = (int)(i8 / ((size_t)192*P_));
  int c = (int)(i8 % 192);
  int bg = b*8 + c/24;
  const double N = 24.0*65536.0;
  double mu = stats[bg*2]/N;
  double var = stats[bg*2+1]/N - mu*mu;
  float rstd = 1.0f/sqrtf((float)var + 1e-5f);
  float mean = (float)mu;
  float4 sA = *(const float4*)&gs[c];
  float4 sB = *(const float4*)&gs[c+4];
  float4 bA = *(const float4*)&gb[c];
  float4 bB = *(const float4*)&gb[c+4];
  float4 v0 = *(const float4*)&x[i8];
  float4 v1 = *(const float4*)&x[i8+4];
  float xin[8] = {v0.x,v0.y,v0.z,v0.w,v1.x,v1.y,v1.z,v1.w};
  float scl[8] = {sA.x,sA.y,sA.z,sA.w,sB.x,sB.y,sB.z,sB.w};
  float bia[8] = {bA.x,bA.y,bA.z,bA.w,bB.x,bB.y,bB.z,bB.w};
  #pragma unroll
  for (int i=0;i<8;i++){
    float xn = (xin[i]-mean)*rstd*scl[i] + bia[i];
    xin[i] = xn*sigmoidf_(xn);
  }
  *(float4*)&x[i8]   = make_float4(xin[0],xin[1],xin[2],xin[3]);
  *(float4*)&x[i8+4] = make_float4(xin[4],xin[5],xin[6],xin[7]);
  #pragma unroll
  for (int i=0;i<8;i++) atomicAdd(&pl[c+i], xin[i]);
  __syncthreads();
  if (t<192) atomicAdd(&pooled[b*192+t], pl[t]);
}

// ---------------- channel gate MLP (pooled holds SUMS; divide here) ----------------
__global__ void k_gate(const float* __restrict__ pooled, const float* __restrict__ gw1,
    const float* __restrict__ gb1, const float* __restrict__ gw2, const float* __restrict__ gb2,
    float* __restrict__ gatef)
{
  __shared__ float hb[2*48];
  int t = threadIdx.x;
  const float inv = 1.f/65536.f;
  if (t<96){
    int b=t/48, j=t%48;
    float a = gb1[j];
    for (int c=0;c<192;c++) a = fmaf(pooled[b*192+c]*inv, gw1[j*192+c], a);
    hb[t] = a*sigmoidf_(a);
  }
  __syncthreads();
  for (int i=t;i<384;i+=256){
    int b=i/192, c=i%192;
    float a = gb2[c];
    for (int j=0;j<48;j++) a = fmaf(hb[b*48+j], gw2[c*48+j], a);
    gatef[i] = 0.5f + sigmoidf_(a);
  }
}

// ---------------- 1x1 residual GEMM via MFMA + fused conf head + final mix ----------------
__global__ __launch_bounds__(256,4) void k_combine(const unsigned short* __restrict__ ctxb,
    const float* __restrict__ h2, const float* __restrict__ rpw, const float* __restrict__ rpb,
    const float* __restrict__ gatef, const float* __restrict__ cw, const float* __restrict__ cbias,
    const float* __restrict__ rs, const float* __restrict__ mix,
    float* __restrict__ out_conf, float* __restrict__ dout)
{
  __shared__ short s_x[256*32];   // 16 KB
  __shared__ short s_w[64*32];    // 4 KB
  __shared__ float s_cw[224];
  __shared__ float s_conf[256];
  int t = threadIdx.x;
  size_t p0 = (size_t)blockIdx.x*256;
  int oc0 = blockIdx.y*64, br = blockIdx.y;
  int wv = t>>6, lane = t&63, l15 = lane&15, quad = lane>>4;
  if (t<224) s_cw[t] = (t<194) ? cw[br*194+t] : 0.f;
  float cdot = cbias[br];
  f32x4 acc[4][4];
  #pragma unroll
  for (int mt=0;mt<4;mt++){
    float4 bv = *(const float4*)&rpb[oc0 + mt*16 + quad*4];
    f32x4 iv; iv.x=bv.x; iv.y=bv.y; iv.z=bv.z; iv.w=bv.w;
    #pragma unroll
    for (int nt=0;nt<4;nt++) acc[mt][nt]=iv;
  }
  int myxor = (t>>1)&3;
  for (int ch=0; ch<7; ch++){
    int ic0 = ch*32;
    __syncthreads();
    for (int f=t; f<1024; f+=256){
      int icq = f&3, px = f>>2;
      uint4 v = *(const uint4*)&ctxb[(p0+px)*ICP1 + ic0 + icq*8];
      *(uint4*)&s_x[px*32 + ((icq ^ ((px>>1)&3)))*8] = v;
    }
    {
      int oc = t&63, icq = t>>6;
      unsigned short h[8];
      #pragma unroll
      for (int j=0;j<8;j++){
        int ic = ic0 + icq*8 + j;
        h[j] = (ic<194) ? f2bf(rpw[(size_t)(oc0+oc)*194 + ic]) : (unsigned short)0;
      }
      *(uint4*)&s_w[oc*32 + ((icq ^ ((oc>>1)&3)))*8] = *(uint4*)h;
    }
    __syncthreads();
    // conf accumulation for own px (= p0 + t)
    #pragma unroll
    for (int icq=0; icq<4; icq++){
      uint4 v = *(const uint4*)&s_x[t*32 + ((icq ^ myxor))*8];
      unsigned wd[4] = {v.x,v.y,v.z,v.w};
      #pragma unroll
      for (int j=0;j<8;j++){
        unsigned bits = wd[j>>1];
        float xf = (j&1) ? __uint_as_float(bits & 0xffff0000u) : __uint_as_float(bits<<16);
        cdot = fmaf(xf, s_cw[ic0 + icq*8 + j], cdot);
      }
    }
    bf16x8 Af[4], Bf[4];
    #pragma unroll
    for (int mt=0;mt<4;mt++){
      int r = mt*16 + l15;
      Af[mt] = *(const bf16x8*)&s_w[r*32 + (((quad ^ ((r>>1)&3)))&3)*8];
    }
    #pragma unroll
    for (int nt=0;nt<4;nt++){
      int r = wv*64 + nt*16 + l15;
      Bf[nt] = *(const bf16x8*)&s_x[r*32 + (((quad ^ ((r>>1)&3)))&3)*8];
    }
    #pragma unroll
    for (int mt=0;mt<4;mt++)
      #pragma unroll
      for (int nt=0;nt<4;nt++)
        acc[mt][nt] = __builtin_amdgcn_mfma_f32_16x16x32_bf16(Af[mt], Bf[nt], acc[mt][nt], 0, 0, 0);
  }
  int b = (int)(p0 >> 16);
  {
    float cfv = sigmoidf_(cdot);
    s_conf[t] = cfv;
    out_conf[(size_t)(b*3+br)*P_ + ((p0 + t) & 65535)] = cfv;
  }
  __syncthreads();
  float trs = tanhf(rs[0]);
  float ms2 = tanhf(mix[0]);
  #pragma unroll
  for (int mt=0;mt<4;mt++){
    int oc = oc0 + mt*16 + quad*4;
    int cc = oc & 63;
    float4 gv = *(const float4*)&gatef[b*192 + oc];
    #pragma unroll
    for (int nt=0;nt<4;nt++){
      int pl = wv*64 + nt*16 + l15;
      size_t pf = p0 + pl;
      int p = (int)(pf & 65535);
      ushort4 fh = *(const ushort4*)&ctxb[pf*ICP1 + oc];
      float4 hv = *(const float4*)&h2[pf*192 + oc];
      float cf = s_conf[pl];
      size_t dst = (size_t)br*OUT_B + ((size_t)(b*64+cc))*P_ + p;
      dout[dst]        = bf2f(fh.x) + ms2*(hv.x*gv.x + trs*acc[mt][nt].x)*cf;
      dout[dst + P_]   = bf2f(fh.y) + ms2*(hv.y*gv.y + trs*acc[mt][nt].y)*cf;
      dout[dst + 2*P_] = bf2f(fh.z) + ms2*(hv.z*gv.z + trs*acc[mt][nt].z)*cf;
      dout[dst + 3*P_] = bf2f(fh.w) + ms2*(hv.w*gv.w + trs*acc[mt][nt].w)*cf;
    }
  }
}

extern "C" void kernel_launch(void* const* d_in, const int* in_sizes, int n_in,
                              void* d_out, int out_size, void* d_ws, size_t ws_size,
                              hipStream_t stream)
{
  const float* vf    = (const float*)d_in[0];
  const float* uvs   = (const float*)d_in[1];
  const float* masks = (const float*)d_in[2];
  const float* wg    = (const float*)d_in[3];
  const float* wb    = (const float*)d_in[4];
  const float* wh    = (const float*)d_in[5];
  const float* c1w = (const float*)d_in[7];
  const float* c1b = (const float*)d_in[8];
  const float* g1s = (const float*)d_in[9];
  const float* g1b = (const float*)d_in[10];
  const float* c2w = (const float*)d_in[11];
  const float* c2b = (const float*)d_in[12];
  const float* g2s = (const float*)d_in[13];
  const float* g2b = (const float*)d_in[14];
  const float* gw1 = (const float*)d_in[15];
  const float* gb1 = (const float*)d_in[16];
  const float* gw2 = (const float*)d_in[17];
  const float* gb2 = (const float*)d_in[18];
  const float* rpw = (const float*)d_in[19];
  const float* rpb = (const float*)d_in[20];
  const float* rs  = (const float*)d_in[21];
  const float* cw  = (const float*)d_in[22];
  const float* cb  = (const float*)d_in[23];
  const float* mix = (const float*)d_in[24];

  char* ws = (char*)d_ws;
  float*          accb  = (float*)(ws + OFF_ACC);
  float*          cntb  = (float*)(ws + OFF_CNT);
  unsigned short* ctxb  = (unsigned short*)(ws + OFF_CTXB);
  unsigned short* h1act = (unsigned short*)(ws + OFF_H1A);
  unsigned short* w1p   = (unsigned short*)(ws + OFF_W1);
  unsigned short* w2p   = (unsigned short*)(ws + OFF_W2);
  float*  h1raw  = (float*)(ws + OFF_ACC);
  float*  h2     = (float*)(ws + OFF_ACC);
  double* stats1 = (double*)(ws + OFF_SM + SM_STATS1);
  double* stats2 = (double*)(ws + OFF_SM + SM_STATS2);
  int*    scale  = (int*)(ws + OFF_SM + SM_SCALE);
  float*  pooled = (float*)(ws + OFF_SM + SM_POOLED);
  float*  gatef  = (float*)(ws + OFF_SM + SM_GATE);
  float*  rawu   = (float*)(ws + OFF_SM + SM_RAWU);

  float* out = (float*)d_out;
  float* out_cov  = out + OUT_COV;
  float* out_unc  = out + OUT_UNC;
  float* out_conf = out + OUT_CONF;

  hipMemsetAsync(ws + OFF_ACC, 0, SZ_ACC + SZ_CNT, stream);
  hipMemsetAsync(ws + OFF_SM, 0, 8192, stream);

  k_prep<<<2808, 256, 0, stream>>>(c1w, c2w, w1p, w2p);
  k_fuse<<<4096, 256, 0, stream>>>(vf, uvs, masks, wg, wb, wh, accb, cntb);
  k_finalize<<<2048, 256, 0, stream>>>(accb, cntb, ctxb, out_cov, rawu, scale);
  k_norm_unc<<<512, 256, 0, stream>>>(ctxb, scale, rawu, out_cov, out_unc);
  k_conv3<ICP1,7><<<dim3(128,3,2), 256, 0, stream>>>(ctxb, w1p, c1b, h1raw, stats1);
  k_gn1_apply<<<12288, 256, 0, stream>>>(h1raw, stats1, g1s, g1b, h1act);
  k_conv3<ICP2,6><<<dim3(128,3,2), 256, 0, stream>>>(h1act, w2p, c2b, h2, stats2);
  k_gn2_apply<<<12288, 256, 0, stream>>>(h2, stats2, g2s, g2b, pooled);
  k_gate<<<1, 256, 0, stream>>>(pooled, gw1, gb1, gw2, gb2, gatef);
  k_combine<<<dim3(512,3), 256, 0, stream>>>(ctxb, h2, rpw, rpb, gatef, cw, cb, rs, mix, out_conf, out);
}